// Round 1
// baseline (131.281 us; speedup 1.0000x reference)
//
#include <hip/hip_runtime.h>

#define B_   32
#define T_   8192
#define F_   16
#define OUT_ 24
#define K1_  10
#define ND   19            // combined kernel width
#define TB   512           // timesteps per main block
#define WROWS 536          // staged window rows: [t0-18, t0+TB+1] + slack
#define H1OFF (WROWS * 8 + 8)   // hi-half LDS offset in shorts (+16B de-alias)

// ws layout (bytes):
// [0, 20480)            w2pk: bf16 packed W-frags [tbl=2][ks=10][lane=64][z=8]
// [20480, 20576)        Bc fp32[24]
// [20576, 102496)       w1t fp32[(k*16+i)*128 + c]  (for head blocks)
#define WS_BC_OFF   20480
#define WS_W1T_OFF  20576

typedef short short8 __attribute__((ext_vector_type(8)));
typedef float float4v __attribute__((ext_vector_type(4)));

__device__ __forceinline__ unsigned short f2bf(float f) {
    unsigned u = __builtin_bit_cast(unsigned, f);
    unsigned r = (u + 0x7fffu + ((u >> 16) & 1u)) >> 16;  // RNE
    return (unsigned short)r;
}

__device__ __forceinline__ short8 cvt8(float4 f0, float4 f1) {
    short8 v;
    v[0] = (short)f2bf(f0.x); v[1] = (short)f2bf(f0.y);
    v[2] = (short)f2bf(f0.z); v[3] = (short)f2bf(f0.w);
    v[4] = (short)f2bf(f1.x); v[5] = (short)f2bf(f1.y);
    v[6] = (short)f2bf(f1.z); v[7] = (short)f2bf(f1.w);
    return v;
}

// ---------------- prep (single kernel; replaces pre+prep):
// blocks 0..159: per-block LDS transpose of w1 (two c-half passes, XOR-swizzled
//   banks) + W2 pack waves. Wave wid=bx*4+(tid>>6) -> (j = wid/20, d = wid%20);
//   j in [0,32) x d in [0,20) covers ALL w2pk slots bijectively; (j>=24 || d>=19)
//   waves write zeros -> no separate memset needed.
//   Block 0 additionally dumps w1t (un-swizzled) to global for the head blocks.
// blocks 160..165: Bc(j), wave-per-j, no LDS.
__global__ __launch_bounds__(256) void prep_kernel(const float* __restrict__ w1,
                                                   const float* __restrict__ b1,
                                                   const float* __restrict__ wf,
                                                   const float* __restrict__ bf,
                                                   unsigned short* __restrict__ w2pk,
                                                   float* __restrict__ bcg,
                                                   float* __restrict__ w1t) {
    int tid = threadIdx.x;
    int bx = blockIdx.x;
    int lane = tid & 63;

    if (bx < 160) {
        __shared__ float wl[160 * 64];          // 40 KB: one c-half of w1, transposed
        int wid = bx * 4 + (tid >> 6);          // 0..639
        int j = wid / 20;
        int d = wid - j * 20;                   // j 0..31, d 0..19
        bool active = (j < 24) && (d < 19);
        int klo = d - 9 > 0 ? d - 9 : 0;
        int khi = d < 9 ? d : 9;

        float p[16];
#pragma unroll
        for (int i = 0; i < 16; ++i) p[i] = 0.f;

        const float4* w4 = (const float4*)w1;
        for (int half = 0; half < 2; ++half) {
            // stage this c-half: coalesced read, swizzled LDS write
            for (int n = 0; n < 10; ++n) {
                int f4 = half * 2560 + n * 256 + tid;
                float4 v = w4[f4];
                int f = f4 * 4;
#pragma unroll
                for (int m = 0; m < 4; ++m) {
                    int ff = f + m;
                    int c = ff / 160;
                    int rem = ff - c * 160;
                    int i = rem / 10;
                    int k = rem - i * 10;
                    int row = k * 16 + i;       // matches w1t row = k*16+i
                    int cc = c - half * 64;
                    float e = (m == 0) ? v.x : (m == 1) ? v.y : (m == 2) ? v.z : v.w;
                    wl[row * 64 + (cc ^ (row & 31))] = e;
                }
            }
            __syncthreads();

            if (active) {
                for (int k = klo; k <= khi; ++k) {
                    float wv = wf[j * 1280 + k * 128 + half * 64 + lane];
                    int rb = (d - k) * 16;
#pragma unroll
                    for (int i = 0; i < 16; ++i) {
                        int row = rb + i;
                        p[i] = fmaf(wv, wl[row * 64 + (lane ^ (row & 31))], p[i]);
                    }
                }
            }
            if (bx == 0) {                      // dump un-swizzled w1t for head
                for (int n = 0; n < 40; ++n) {
                    int idx = n * 256 + tid;    // 10240 per half
                    int row = idx >> 6, cc = idx & 63;
                    w1t[row * 128 + half * 64 + cc] = wl[row * 64 + (cc ^ (row & 31))];
                }
            }
            if (half == 0) __syncthreads();     // drain before restage
        }

#pragma unroll
        for (int i = 0; i < 16; ++i) {
            p[i] += __shfl_xor(p[i], 1);
            p[i] += __shfl_xor(p[i], 2);
            p[i] += __shfl_xor(p[i], 4);
            p[i] += __shfl_xor(p[i], 8);
            p[i] += __shfl_xor(p[i], 16);
            p[i] += __shfl_xor(p[i], 32);
        }
        if (lane < 16) {
            float v = p[0];
#pragma unroll
            for (int i = 1; i < 16; ++i)
                if (lane == i) v = p[i];
            int kk = d * 16 + lane;
            int ks = kk >> 5, r = kk & 31;
            int quad = r >> 3, z = r & 7;
            int tbl = j >> 4, jj = j & 15;
            int lt = jj + quad * 16;
            w2pk[((tbl * 10 + ks) * 64 + lt) * 8 + z] = f2bf(v);
        }
    } else {
        // Bc(j): bcg[j] = bf[j] + sum_k sum_c wf[j,k,c] * b1[c]
        int j = (bx - 160) * 4 + (tid >> 6);    // 0..23
        float s0 = 0.f, s1 = 0.f;
#pragma unroll
        for (int k = 0; k < K1_; ++k) {
            s0 += wf[j * 1280 + k * 128 + lane];
            s1 += wf[j * 1280 + k * 128 + 64 + lane];
        }
        float s = s0 * b1[lane] + s1 * b1[64 + lane];
        s += __shfl_xor(s, 1);
        s += __shfl_xor(s, 2);
        s += __shfl_xor(s, 4);
        s += __shfl_xor(s, 8);
        s += __shfl_xor(s, 16);
        s += __shfl_xor(s, 32);
        if (lane == 0) bcg[j] = bf[j] + s;
    }
}

// ---------------- main: transposed MFMA GEMM (W=A, x=B), fused fp32->bf16 LDS staging.
// grid (17, 32): x=0..15 GEMM over 512 t each; x==16 head (t<9) computed DIRECTLY
// from w1t/wf/b1/bf (no E table): h[c,u] then y[t,j] with h[0]-replication.
__global__ __launch_bounds__(256) void main_kernel(const float* __restrict__ x,
                                                   const unsigned short* __restrict__ w2pk,
                                                   const float* __restrict__ bcg,
                                                   float* __restrict__ out,
                                                   const float* __restrict__ w1t,
                                                   const float* __restrict__ wf,
                                                   const float* __restrict__ b1,
                                                   const float* __restrict__ bf) {
    int tid = threadIdx.x;
    int b = blockIdx.y;
    __shared__ __align__(16) short xls[2 * WROWS * 8 + 8];   // 17168 B (reused by head)

    if (blockIdx.x == 16) {    // head: t in [0,9)
        float* xh   = (float*)xls;       // [19][16] x rows -9..9 (zero-padded)
        float* hbuf = xh + 304;          // [10][132] h[u][c] (+pad)

        for (int idx = tid; idx < 304; idx += 256) {
            int m = idx >> 4, i = idx & 15;
            int tr = m - 9;
            xh[idx] = (tr >= 0) ? x[((long)b * T_ + tr) * 16 + i] : 0.f;
        }
        __syncthreads();

        // phase 1: h[c,u] = b1[c] + sum_{kap,i} w1[c,i,kap] * x[u+kap-9, i]
        int c = tid & 127, uh = tid >> 7;        // uh 0..1 -> u = uh*5 + uu
        float hacc[5];
        float bv = b1[c];
#pragma unroll
        for (int uu = 0; uu < 5; ++uu) hacc[uu] = bv;
        const float* xu = xh + (uh * 5) * 16;    // xh[u*16 + r] with r = kap*16+i
        for (int r = 0; r < 160; ++r) {
            float wv = w1t[r * 128 + c];
#pragma unroll
            for (int uu = 0; uu < 5; ++uu)
                hacc[uu] = fmaf(wv, xu[uu * 16 + r], hacc[uu]);
        }
#pragma unroll
        for (int uu = 0; uu < 5; ++uu) hbuf[(uh * 5 + uu) * 132 + c] = hacc[uu];
        __syncthreads();

        // phase 2: y[t,j] = bf[j] + sum_{k,c} wf[j,k,c] * h[max(t+k-9,0)][c]
        if (tid < 9 * OUT_) {
            int t = tid / OUT_, j = tid - (tid / OUT_) * OUT_;
            float ax = 0.f, ay = 0.f, az = 0.f, aw = 0.f;
            for (int k = 0; k < K1_; ++k) {
                int m = t + k - 9; if (m < 0) m = 0;
                const float4* hv = (const float4*)(hbuf + m * 132);
                const float4* wv = (const float4*)(wf + j * 1280 + k * 128);
#pragma unroll
                for (int q = 0; q < 32; ++q) {
                    float4 h4 = hv[q];
                    float4 w4 = wv[q];
                    ax = fmaf(w4.x, h4.x, ax);
                    ay = fmaf(w4.y, h4.y, ay);
                    az = fmaf(w4.z, h4.z, az);
                    aw = fmaf(w4.w, h4.w, aw);
                }
            }
            out[((long)b * T_ + t) * OUT_ + j] = bf[j] + ((ax + ay) + (az + aw));
        }
        return;
    }

    int t0 = blockIdx.x * TB;

    // stage x window: global fp32 (coalesced) -> bf16 -> LDS; zero outside [0,T)
    for (int idx = tid; idx < 2 * WROWS; idx += 256) {
        int h = idx >= WROWS;
        int row = h ? idx - WROWS : idx;
        int t = t0 - 18 + row;
        short8 v = short8{0, 0, 0, 0, 0, 0, 0, 0};
        if (t >= 0 && t < T_) {
            const float4* p = (const float4*)(x + ((long)b * T_ + t) * 16 + h * 8);
            v = cvt8(p[0], p[1]);
        }
        *(short8*)(xls + h * H1OFF + row * 8) = v;
    }

    int lane = tid & 63, w = tid >> 6;
    int t = lane & 15, q = lane >> 4;
    int h = q & 1, qh = q >> 1;

    // W A-frags: read once per wave (coalesced 1KB loads, L1-hot)
    const unsigned short* pk0 = w2pk + lane * 8;          // tbl0: j = 0..15
    const unsigned short* pk1 = w2pk + 5120 + lane * 8;   // tbl1: j = 16..23 (+zero pad)
    short8 W0[10], W1[10];
#pragma unroll
    for (int ks = 0; ks < 10; ++ks) {
        W0[ks] = *(const short8*)(pk0 + ks * 512);
        W1[ks] = *(const short8*)(pk1 + ks * 512);
    }

    __syncthreads();

    const short* ap = xls + h * H1OFF + (w * 128 + t + qh) * 8;

    float4v acc[8][2];
#pragma unroll
    for (int mt = 0; mt < 8; ++mt) {
        acc[mt][0] = float4v{0.f, 0.f, 0.f, 0.f};
        acc[mt][1] = float4v{0.f, 0.f, 0.f, 0.f};
    }

#pragma unroll
    for (int ks = 0; ks < 10; ++ks) {
#pragma unroll
        for (int mt = 0; mt < 8; ++mt) {
            short8 xf = *(const short8*)(ap + (mt * 16 + 2 * ks) * 8);
            acc[mt][0] = __builtin_amdgcn_mfma_f32_16x16x32_bf16(W0[ks], xf, acc[mt][0], 0, 0, 0);
            acc[mt][1] = __builtin_amdgcn_mfma_f32_16x16x32_bf16(W1[ks], xf, acc[mt][1], 0, 0, 0);
        }
    }

    // epilogue: C col = t, row = j = q*4+reg (+16 for tbl1) -> float4 stores
    long outb = (long)b * T_;
    float4 bc0 = *(const float4*)(bcg + q * 4);
    float4 bc1 = (q < 2) ? *(const float4*)(bcg + 16 + q * 4) : make_float4(0.f, 0.f, 0.f, 0.f);
    bool edge = (blockIdx.x == 0);
#pragma unroll
    for (int mt = 0; mt < 8; ++mt) {
        int t_out = t0 + w * 128 + mt * 16 + t;
        if (!edge || t_out >= 9) {        // t<9 owned by head
            float* o = out + (outb + t_out) * OUT_;
            float4 v0 = make_float4(acc[mt][0][0] + bc0.x, acc[mt][0][1] + bc0.y,
                                    acc[mt][0][2] + bc0.z, acc[mt][0][3] + bc0.w);
            *(float4*)(o + q * 4) = v0;
            if (q < 2) {
                float4 v1 = make_float4(acc[mt][1][0] + bc1.x, acc[mt][1][1] + bc1.y,
                                        acc[mt][1][2] + bc1.z, acc[mt][1][3] + bc1.w);
                *(float4*)(o + 16 + q * 4) = v1;
            }
        }
    }
}

extern "C" void kernel_launch(void* const* d_in, const int* in_sizes, int n_in,
                              void* d_out, int out_size, void* d_ws, size_t ws_size,
                              hipStream_t stream) {
    const float* x  = (const float*)d_in[0];
    const float* w1 = (const float*)d_in[1];
    const float* b1 = (const float*)d_in[2];
    const float* wf = (const float*)d_in[3];
    const float* bf = (const float*)d_in[4];
    float* out = (float*)d_out;
    unsigned short* w2pk = (unsigned short*)d_ws;
    float* bcg = (float*)((char*)d_ws + WS_BC_OFF);
    float* w1t = (float*)((char*)d_ws + WS_W1T_OFF);

    hipLaunchKernelGGL(prep_kernel, dim3(166), dim3(256), 0, stream,
                       w1, b1, wf, bf, w2pk, bcg, w1t);
    hipLaunchKernelGGL(main_kernel, dim3(17, B_), dim3(256), 0, stream,
                       x, w2pk, bcg, out, w1t, wf, b1, bf);
}

// Round 2
// 128.577 us; speedup vs baseline: 1.0210x; 1.0210x over previous
//
#include <hip/hip_runtime.h>

#define B_   32
#define T_   8192
#define F_   16
#define OUT_ 24
#define K1_  10
#define ND   19            // combined kernel width
#define TB   512           // timesteps per main block
#define WROWS 536          // staged window rows: [t0-18, t0+TB+1] + slack
#define H1OFF (WROWS * 8 + 8)   // hi-half LDS offset in shorts (+16B de-alias)

// ws layout (bytes):
// [0, 20480)            w2pk: bf16 packed W-frags [tbl=2][ks=10][lane=64][z=8]
// [20480, 20576)        Bc fp32[24]
#define WS_BC_OFF   20480

typedef short short8 __attribute__((ext_vector_type(8)));
typedef float float4v __attribute__((ext_vector_type(4)));

__device__ __forceinline__ unsigned short f2bf(float f) {
    unsigned u = __builtin_bit_cast(unsigned, f);
    unsigned r = (u + 0x7fffu + ((u >> 16) & 1u)) >> 16;  // RNE
    return (unsigned short)r;
}

__device__ __forceinline__ short8 cvt8(float4 f0, float4 f1) {
    short8 v;
    v[0] = (short)f2bf(f0.x); v[1] = (short)f2bf(f0.y);
    v[2] = (short)f2bf(f0.z); v[3] = (short)f2bf(f0.w);
    v[4] = (short)f2bf(f1.x); v[5] = (short)f2bf(f1.y);
    v[6] = (short)f2bf(f1.z); v[7] = (short)f2bf(f1.w);
    return v;
}

// stage one c-half of w1 into LDS, transposed to wl[row=k*16+i][cc] with
// XOR bank swizzle (cc ^ (row&31)); coalesced float4 global reads.
__device__ __forceinline__ void stage_w1_half(const float4* __restrict__ w4,
                                              float* __restrict__ wl,
                                              int tid, int half) {
    for (int n = 0; n < 10; ++n) {
        int f4 = half * 2560 + n * 256 + tid;
        float4 v = w4[f4];
        int f = f4 * 4;
#pragma unroll
        for (int m = 0; m < 4; ++m) {
            int ff = f + m;
            int c = ff / 160;
            int rem = ff - c * 160;
            int i = rem / 10;
            int k = rem - i * 10;
            int row = k * 16 + i;       // w1t row = k*16+i
            int cc = c - half * 64;
            float e = (m == 0) ? v.x : (m == 1) ? v.y : (m == 2) ? v.z : v.w;
            wl[row * 64 + (cc ^ (row & 31))] = e;
        }
    }
}

// ---------------- prep (single kernel):
// blocks 0..159: per-block LDS transpose of w1 + W2 pack waves.
//   Wave wid=bx*4+(tid>>6) -> (j = wid/20, d = wid%20); j in [0,32) x d in [0,20)
//   covers ALL w2pk slots bijectively; (j>=24 || d>=19) waves write zeros.
// blocks 160..165: Bc(j), wave-per-j, no LDS.
// blocks 166..197: HEAD for b = bx-166: computes out[b, t<9, :] directly.
//   Per c-half: stage w1 half in LDS, h[u][c] via pure-LDS FMA; then phase-2
//   dots against wf (L2-hot). No serial global-load chains anywhere.
__global__ __launch_bounds__(256) void prep_kernel(const float* __restrict__ w1,
                                                   const float* __restrict__ b1,
                                                   const float* __restrict__ wf,
                                                   const float* __restrict__ bf,
                                                   const float* __restrict__ x,
                                                   unsigned short* __restrict__ w2pk,
                                                   float* __restrict__ bcg,
                                                   float* __restrict__ out) {
    int tid = threadIdx.x;
    int bx = blockIdx.x;
    int lane = tid & 63;

    __shared__ __align__(16) float smem[160 * 64 + 304 + 1320];  // wl | xh | hbuf

    if (bx < 160) {
        float* wl = smem;                       // 40 KB: one c-half of w1, transposed
        int wid = bx * 4 + (tid >> 6);          // 0..639
        int j = wid / 20;
        int d = wid - j * 20;                   // j 0..31, d 0..19
        bool active = (j < 24) && (d < 19);
        int klo = d - 9 > 0 ? d - 9 : 0;
        int khi = d < 9 ? d : 9;

        float p[16];
#pragma unroll
        for (int i = 0; i < 16; ++i) p[i] = 0.f;

        for (int half = 0; half < 2; ++half) {
            if (half) __syncthreads();          // drain half-0 readers before restage
            stage_w1_half((const float4*)w1, wl, tid, half);
            __syncthreads();

            if (active) {
                for (int k = klo; k <= khi; ++k) {
                    float wv = wf[j * 1280 + k * 128 + half * 64 + lane];
                    int rb = (d - k) * 16;
#pragma unroll
                    for (int i = 0; i < 16; ++i) {
                        int row = rb + i;
                        p[i] = fmaf(wv, wl[row * 64 + (lane ^ (row & 31))], p[i]);
                    }
                }
            }
        }

#pragma unroll
        for (int i = 0; i < 16; ++i) {
            p[i] += __shfl_xor(p[i], 1);
            p[i] += __shfl_xor(p[i], 2);
            p[i] += __shfl_xor(p[i], 4);
            p[i] += __shfl_xor(p[i], 8);
            p[i] += __shfl_xor(p[i], 16);
            p[i] += __shfl_xor(p[i], 32);
        }
        if (lane < 16) {
            float v = p[0];
#pragma unroll
            for (int i = 1; i < 16; ++i)
                if (lane == i) v = p[i];
            int kk = d * 16 + lane;
            int ks = kk >> 5, r = kk & 31;
            int quad = r >> 3, z = r & 7;
            int tbl = j >> 4, jj = j & 15;
            int lt = jj + quad * 16;
            w2pk[((tbl * 10 + ks) * 64 + lt) * 8 + z] = f2bf(v);
        }
    } else if (bx < 166) {
        // Bc(j): bcg[j] = bf[j] + sum_k sum_c wf[j,k,c] * b1[c]
        int j = (bx - 160) * 4 + (tid >> 6);    // 0..23
        float s0 = 0.f, s1 = 0.f;
#pragma unroll
        for (int k = 0; k < K1_; ++k) {
            s0 += wf[j * 1280 + k * 128 + lane];
            s1 += wf[j * 1280 + k * 128 + 64 + lane];
        }
        float s = s0 * b1[lane] + s1 * b1[64 + lane];
        s += __shfl_xor(s, 1);
        s += __shfl_xor(s, 2);
        s += __shfl_xor(s, 4);
        s += __shfl_xor(s, 8);
        s += __shfl_xor(s, 16);
        s += __shfl_xor(s, 32);
        if (lane == 0) bcg[j] = bf[j] + s;
    } else {
        // HEAD: b = bx - 166; out rows t in [0,9)
        int b = bx - 166;
        float* wl   = smem;                     // [160][64] swizzled w1 half
        float* xh   = smem + 10240;             // [19][16] x rows -9..9 (zero-pad)
        float* hbuf = smem + 10544;             // [10][132] h[u][c] (+pad)

        for (int idx = tid; idx < 304; idx += 256) {
            int m = idx >> 4, i = idx & 15;
            int tr = m - 9;
            xh[idx] = (tr >= 0) ? x[((long)b * T_ + tr) * 16 + i] : 0.f;
        }

        int ug = tid >> 6;                      // wave id 0..3
        for (int half = 0; half < 2; ++half) {
            if (half) __syncthreads();          // drain half-0 wl readers
            stage_w1_half((const float4*)w1, wl, tid, half);
            __syncthreads();                    // also covers xh writes (half 0)

            // h[u][c] = b1[c] + sum_r wl[r][c] * xh[u*16 + r], c in this half
            int c = half * 64 + lane;
            float bv = b1[c];
            float hacc[3];
#pragma unroll
            for (int s = 0; s < 3; ++s) hacc[s] = bv;
#pragma unroll 4
            for (int r = 0; r < 160; ++r) {
                float wv = wl[r * 64 + (lane ^ (r & 31))];
#pragma unroll
                for (int s = 0; s < 3; ++s) {
                    int u = ug + 4 * s; if (u > 9) u = 0;   // lanes u>=10 compute junk, discarded
                    hacc[s] = fmaf(wv, xh[u * 16 + r], hacc[s]);
                }
            }
#pragma unroll
            for (int s = 0; s < 3; ++s) {
                int u = ug + 4 * s;
                if (u < 10) hbuf[u * 132 + c] = hacc[s];
            }
        }
        __syncthreads();

        // phase 2: y[t,j] = bf[j] + sum_{k,c} wf[j,k,c] * h[max(t+k-9,0)][c]
        if (tid < 9 * OUT_) {
            int t = tid / OUT_, j = tid - (tid / OUT_) * OUT_;
            float ax = 0.f, ay = 0.f, az = 0.f, aw = 0.f;
            for (int k = 0; k < K1_; ++k) {
                int m = t + k - 9; if (m < 0) m = 0;
                const float4* hv = (const float4*)(hbuf + m * 132);
                const float4* wv = (const float4*)(wf + j * 1280 + k * 128);
#pragma unroll
                for (int q = 0; q < 32; ++q) {
                    float4 h4 = hv[q];
                    float4 w4 = wv[q];
                    ax = fmaf(w4.x, h4.x, ax);
                    ay = fmaf(w4.y, h4.y, ay);
                    az = fmaf(w4.z, h4.z, az);
                    aw = fmaf(w4.w, h4.w, aw);
                }
            }
            out[((long)b * T_ + t) * OUT_ + j] = bf[j] + ((ax + ay) + (az + aw));
        }
    }
}

// ---------------- main: pure transposed MFMA GEMM (W=A, x=B), fused fp32->bf16
// LDS staging. grid (16, 32): 512 t per block. t<9 owned by prep's head blocks.
__global__ __launch_bounds__(256) void main_kernel(const float* __restrict__ x,
                                                   const unsigned short* __restrict__ w2pk,
                                                   const float* __restrict__ bcg,
                                                   float* __restrict__ out) {
    int tid = threadIdx.x;
    int b = blockIdx.y;
    __shared__ __align__(16) short xls[2 * WROWS * 8 + 8];   // 17168 B

    int t0 = blockIdx.x * TB;

    // stage x window: global fp32 (coalesced) -> bf16 -> LDS; zero outside [0,T)
    for (int idx = tid; idx < 2 * WROWS; idx += 256) {
        int h = idx >= WROWS;
        int row = h ? idx - WROWS : idx;
        int t = t0 - 18 + row;
        short8 v = short8{0, 0, 0, 0, 0, 0, 0, 0};
        if (t >= 0 && t < T_) {
            const float4* p = (const float4*)(x + ((long)b * T_ + t) * 16 + h * 8);
            v = cvt8(p[0], p[1]);
        }
        *(short8*)(xls + h * H1OFF + row * 8) = v;
    }

    int lane = tid & 63, w = tid >> 6;
    int t = lane & 15, q = lane >> 4;
    int h = q & 1, qh = q >> 1;

    // W A-frags: read once per wave (coalesced 1KB loads, L1-hot)
    const unsigned short* pk0 = w2pk + lane * 8;          // tbl0: j = 0..15
    const unsigned short* pk1 = w2pk + 5120 + lane * 8;   // tbl1: j = 16..23 (+zero pad)
    short8 W0[10], W1[10];
#pragma unroll
    for (int ks = 0; ks < 10; ++ks) {
        W0[ks] = *(const short8*)(pk0 + ks * 512);
        W1[ks] = *(const short8*)(pk1 + ks * 512);
    }

    __syncthreads();

    const short* ap = xls + h * H1OFF + (w * 128 + t + qh) * 8;

    float4v acc[8][2];
#pragma unroll
    for (int mt = 0; mt < 8; ++mt) {
        acc[mt][0] = float4v{0.f, 0.f, 0.f, 0.f};
        acc[mt][1] = float4v{0.f, 0.f, 0.f, 0.f};
    }

#pragma unroll
    for (int ks = 0; ks < 10; ++ks) {
#pragma unroll
        for (int mt = 0; mt < 8; ++mt) {
            short8 xf = *(const short8*)(ap + (mt * 16 + 2 * ks) * 8);
            acc[mt][0] = __builtin_amdgcn_mfma_f32_16x16x32_bf16(W0[ks], xf, acc[mt][0], 0, 0, 0);
            acc[mt][1] = __builtin_amdgcn_mfma_f32_16x16x32_bf16(W1[ks], xf, acc[mt][1], 0, 0, 0);
        }
    }

    // epilogue: C col = t, row = j = q*4+reg (+16 for tbl1) -> float4 stores
    long outb = (long)b * T_;
    float4 bc0 = *(const float4*)(bcg + q * 4);
    float4 bc1 = (q < 2) ? *(const float4*)(bcg + 16 + q * 4) : make_float4(0.f, 0.f, 0.f, 0.f);
    bool edge = (blockIdx.x == 0);
#pragma unroll
    for (int mt = 0; mt < 8; ++mt) {
        int t_out = t0 + w * 128 + mt * 16 + t;
        if (!edge || t_out >= 9) {        // t<9 owned by head
            float* o = out + (outb + t_out) * OUT_;
            float4 v0 = make_float4(acc[mt][0][0] + bc0.x, acc[mt][0][1] + bc0.y,
                                    acc[mt][0][2] + bc0.z, acc[mt][0][3] + bc0.w);
            *(float4*)(o + q * 4) = v0;
            if (q < 2) {
                float4 v1 = make_float4(acc[mt][1][0] + bc1.x, acc[mt][1][1] + bc1.y,
                                        acc[mt][1][2] + bc1.z, acc[mt][1][3] + bc1.w);
                *(float4*)(o + 16 + q * 4) = v1;
            }
        }
    }
}

extern "C" void kernel_launch(void* const* d_in, const int* in_sizes, int n_in,
                              void* d_out, int out_size, void* d_ws, size_t ws_size,
                              hipStream_t stream) {
    const float* x  = (const float*)d_in[0];
    const float* w1 = (const float*)d_in[1];
    const float* b1 = (const float*)d_in[2];
    const float* wf = (const float*)d_in[3];
    const float* bf = (const float*)d_in[4];
    float* out = (float*)d_out;
    unsigned short* w2pk = (unsigned short*)d_ws;
    float* bcg = (float*)((char*)d_ws + WS_BC_OFF);

    hipLaunchKernelGGL(prep_kernel, dim3(198), dim3(256), 0, stream,
                       w1, b1, wf, bf, x, w2pk, bcg, out);
    hipLaunchKernelGGL(main_kernel, dim3(16, B_), dim3(256), 0, stream,
                       x, w2pk, bcg, out);
}

// Round 3
// 93.671 us; speedup vs baseline: 1.4015x; 1.3726x over previous
//
#include <hip/hip_runtime.h>

#define B_   32
#define T_   8192
#define F_   16
#define OUT_ 24
#define K1_  10
#define ND   19            // combined kernel width
#define JP   32            // padded N
#define TB   512           // timesteps per main block
#define WROWS 536          // staged window rows: [t0-18, t0+TB+1] + slack
#define H1OFF (WROWS * 8 + 8)   // hi-half LDS offset in shorts (+16B de-alias)

// ws layout (bytes):
// [0, 20480)            w2pk: bf16 packed W-frags [tbl=2][ks=10][lane=64][z=8]
// [20480, 20576)        Bc fp32[24]
// [20576, 144992)       E fp32[9][24][9][16]
// [144992, 226912)      w1t fp32[(k*16+i)*128 + c]
#define WS_BC_OFF   20480
#define WS_E_OFF    20576
#define WS_W1T_OFF  144992

typedef short short8 __attribute__((ext_vector_type(8)));
typedef float float4v __attribute__((ext_vector_type(4)));

__device__ __forceinline__ unsigned short f2bf(float f) {
    unsigned u = __builtin_bit_cast(unsigned, f);
    unsigned r = (u + 0x7fffu + ((u >> 16) & 1u)) >> 16;  // RNE
    return (unsigned short)r;
}

__device__ __forceinline__ short8 cvt8(float4 f0, float4 f1) {
    short8 v;
    v[0] = (short)f2bf(f0.x); v[1] = (short)f2bf(f0.y);
    v[2] = (short)f2bf(f0.z); v[3] = (short)f2bf(f0.w);
    v[4] = (short)f2bf(f1.x); v[5] = (short)f2bf(f1.y);
    v[6] = (short)f2bf(f1.z); v[7] = (short)f2bf(f1.w);
    return v;
}

// ---------------- pre (tiny): w1t transpose (blocks 0..79) + w2pk zero (80..119)
__global__ __launch_bounds__(256) void pre_kernel(const float* __restrict__ w1,
                                                  float* __restrict__ w1t,
                                                  unsigned short* __restrict__ w2pk) {
    int bx = blockIdx.x;
    int tid = threadIdx.x;
    if (bx < 80) {
        int idx = bx * 256 + tid;                // 20480 elems
        float v = w1[idx];
        int c = idx / 160;
        int rem = idx - c * 160;
        int i = rem / 10;
        int k = rem - i * 10;
        w1t[(k * 16 + i) * 128 + c] = v;
    } else {
        int idx = (bx - 80) * 256 + tid;         // 10240 uints
        ((unsigned*)w2pk)[idx] = 0;
    }
}

// ---------------- prep: wave-per-task, no barriers.
// waves 0..455: W2(j,d); 456..479: Bc(j); 480..2423: E(t,j,tau). grid 606 x 256.
__global__ __launch_bounds__(256) void prep_kernel(const float* __restrict__ w1t,
                                                   const float* __restrict__ b1,
                                                   const float* __restrict__ wf,
                                                   const float* __restrict__ bf,
                                                   unsigned short* __restrict__ w2pk,
                                                   float* __restrict__ bcg,
                                                   float* __restrict__ Eg) {
    int tid = threadIdx.x;
    int lane = tid & 63;
    int wid = blockIdx.x * 4 + (tid >> 6);

    if (wid < 456) {
        int j = wid / ND, d = wid % ND;
        float p[16];
#pragma unroll
        for (int i = 0; i < 16; ++i) p[i] = 0.f;
        int klo = d - 9 > 0 ? d - 9 : 0;
        int khi = d < 9 ? d : 9;
        for (int k = klo; k <= khi; ++k) {
            float w0 = wf[j * 1280 + k * 128 + lane];
            float w1v = wf[j * 1280 + k * 128 + 64 + lane];
            const float* wb = w1t + (d - k) * 16 * 128;
#pragma unroll
            for (int i = 0; i < 16; ++i)
                p[i] = fmaf(w0, wb[i * 128 + lane], fmaf(w1v, wb[i * 128 + 64 + lane], p[i]));
        }
#pragma unroll
        for (int i = 0; i < 16; ++i) {
            p[i] += __shfl_xor(p[i], 1);
            p[i] += __shfl_xor(p[i], 2);
            p[i] += __shfl_xor(p[i], 4);
            p[i] += __shfl_xor(p[i], 8);
            p[i] += __shfl_xor(p[i], 16);
            p[i] += __shfl_xor(p[i], 32);
        }
        if (lane < 16) {
            float v = p[0];
#pragma unroll
            for (int i = 1; i < 16; ++i)
                if (lane == i) v = p[i];
            int kk = d * 16 + lane;
            int ks = kk >> 5, r = kk & 31;
            int quad = r >> 3, z = r & 7;
            int tbl = j >> 4, jj = j & 15;
            int lt = jj + quad * 16;
            w2pk[((tbl * 10 + ks) * 64 + lt) * 8 + z] = f2bf(v);
        }
    } else if (wid < 480) {
        int j = wid - 456;
        float s0 = 0.f, s1 = 0.f;
#pragma unroll
        for (int k = 0; k < K1_; ++k) {
            s0 += wf[j * 1280 + k * 128 + lane];
            s1 += wf[j * 1280 + k * 128 + 64 + lane];
        }
        float s = s0 * b1[lane] + s1 * b1[64 + lane];
        s += __shfl_xor(s, 1);
        s += __shfl_xor(s, 2);
        s += __shfl_xor(s, 4);
        s += __shfl_xor(s, 8);
        s += __shfl_xor(s, 16);
        s += __shfl_xor(s, 32);
        if (lane == 0) bcg[j] = bf[j] + s;
    } else {
        int eidx = wid - 480;                 // 0..1943
        int t = eidx / 216;
        int rem = eidx % 216;
        int j = rem / 9, tau = rem % 9;
        float p[16];
#pragma unroll
        for (int i = 0; i < 16; ++i) p[i] = 0.f;
        for (int k = 0; k < K1_; ++k) {
            int u = t + k - 9; if (u < 0) u = 0;
            if (tau > u) continue;
            int kap = tau + 9 - u;
            float w0 = wf[j * 1280 + k * 128 + lane];
            float w1v = wf[j * 1280 + k * 128 + 64 + lane];
            const float* wb = w1t + kap * 16 * 128;
#pragma unroll
            for (int i = 0; i < 16; ++i)
                p[i] = fmaf(w0, wb[i * 128 + lane], fmaf(w1v, wb[i * 128 + 64 + lane], p[i]));
        }
#pragma unroll
        for (int i = 0; i < 16; ++i) {
            p[i] += __shfl_xor(p[i], 1);
            p[i] += __shfl_xor(p[i], 2);
            p[i] += __shfl_xor(p[i], 4);
            p[i] += __shfl_xor(p[i], 8);
            p[i] += __shfl_xor(p[i], 16);
            p[i] += __shfl_xor(p[i], 32);
        }
        if (lane < 16) {
            float v = p[0];
#pragma unroll
            for (int i = 1; i < 16; ++i)
                if (lane == i) v = p[i];
            Eg[((t * OUT_ + j) * 9 + tau) * 16 + lane] = v;
        }
    }
}

// ---------------- main: transposed MFMA GEMM (W=A, x=B), fused fp32->bf16 LDS staging.
// grid (17, 32): x=0..15 GEMM over 512 t each; x==16 head (t<9).
// acc split into two mt-passes of 4 (reg reuse via #pragma unroll 1) to cut VGPR
// and raise occupancy; __launch_bounds__(256,3) caps allocation at 3 waves/SIMD.
__global__ __launch_bounds__(256, 3) void main_kernel(const float* __restrict__ x,
                                                   const unsigned short* __restrict__ w2pk,
                                                   const float* __restrict__ bcg,
                                                   float* __restrict__ out,
                                                   const float* __restrict__ Eg) {
    int tid = threadIdx.x;
    int b = blockIdx.y;

    if (blockIdx.x == 16) {    // head: t in [0,9)
        if (tid >= 9 * OUT_) return;
        int t = tid / OUT_, j = tid % OUT_;
        const float4* xv = (const float4*)(x + (long)b * T_ * F_);
        const float4* ev = (const float4*)(Eg + (long)tid * 144);
        float ax = 0.f, ay = 0.f, az = 0.f, aw = 0.f;
#pragma unroll
        for (int q = 0; q < 36; ++q) {
            float4 e = ev[q];
            float4 v = xv[q];
            ax = fmaf(e.x, v.x, ax);
            ay = fmaf(e.y, v.y, ay);
            az = fmaf(e.z, v.z, az);
            aw = fmaf(e.w, v.w, aw);
        }
        out[((long)b * T_ + t) * OUT_ + j] = bcg[j] + ((ax + ay) + (az + aw));
        return;
    }

    __shared__ short xls[2 * WROWS * 8 + 8];   // 17168 B: lo-half @0, hi-half @H1OFF
    int t0 = blockIdx.x * TB;

    // stage x window: global fp32 (coalesced) -> bf16 -> LDS; zero outside [0,T)
    for (int idx = tid; idx < 2 * WROWS; idx += 256) {
        int h = idx >= WROWS;
        int row = h ? idx - WROWS : idx;
        int t = t0 - 18 + row;
        short8 v = short8{0, 0, 0, 0, 0, 0, 0, 0};
        if (t >= 0 && t < T_) {
            const float4* p = (const float4*)(x + ((long)b * T_ + t) * 16 + h * 8);
            v = cvt8(p[0], p[1]);
        }
        *(short8*)(xls + h * H1OFF + row * 8) = v;
    }

    int lane = tid & 63, w = tid >> 6;
    int t = lane & 15, q = lane >> 4;
    int h = q & 1, qh = q >> 1;

    // W A-frags: read once per wave (coalesced 1KB loads, L1-hot)
    const unsigned short* pk0 = w2pk + lane * 8;          // tbl0: j = 0..15
    const unsigned short* pk1 = w2pk + 5120 + lane * 8;   // tbl1: j = 16..31
    short8 W0[10], W1[10];
#pragma unroll
    for (int ks = 0; ks < 10; ++ks) {
        W0[ks] = *(const short8*)(pk0 + ks * 512);
        W1[ks] = *(const short8*)(pk1 + ks * 512);
    }

    __syncthreads();

    const short* ap = xls + h * H1OFF + (w * 128 + t + qh) * 8;

    long outb = (long)b * T_;
    float4 bc0 = *(const float4*)(bcg + q * 4);
    float4 bc1 = (q < 2) ? *(const float4*)(bcg + 16 + q * 4) : make_float4(0.f, 0.f, 0.f, 0.f);
    bool edge = (blockIdx.x == 0);

    float4v acc[4][2];
#pragma unroll 1
    for (int pass = 0; pass < 2; ++pass) {
#pragma unroll
        for (int mt = 0; mt < 4; ++mt) {
            acc[mt][0] = float4v{0.f, 0.f, 0.f, 0.f};
            acc[mt][1] = float4v{0.f, 0.f, 0.f, 0.f};
        }

#pragma unroll
        for (int ks = 0; ks < 10; ++ks) {
#pragma unroll
            for (int mt = 0; mt < 4; ++mt) {
                short8 xf = *(const short8*)(ap + ((pass * 4 + mt) * 16 + 2 * ks) * 8);
                acc[mt][0] = __builtin_amdgcn_mfma_f32_16x16x32_bf16(W0[ks], xf, acc[mt][0], 0, 0, 0);
                acc[mt][1] = __builtin_amdgcn_mfma_f32_16x16x32_bf16(W1[ks], xf, acc[mt][1], 0, 0, 0);
            }
        }

        // epilogue: C col = t, row = j = q*4+reg (+16 for tbl1) -> float4 stores
#pragma unroll
        for (int mt = 0; mt < 4; ++mt) {
            int t_out = t0 + w * 128 + (pass * 4 + mt) * 16 + t;
            if (!edge || t_out >= 9) {        // t<9 owned by head
                float* o = out + (outb + t_out) * OUT_;
                float4 v0 = make_float4(acc[mt][0][0] + bc0.x, acc[mt][0][1] + bc0.y,
                                        acc[mt][0][2] + bc0.z, acc[mt][0][3] + bc0.w);
                *(float4*)(o + q * 4) = v0;
                if (q < 2) {
                    float4 v1 = make_float4(acc[mt][1][0] + bc1.x, acc[mt][1][1] + bc1.y,
                                            acc[mt][1][2] + bc1.z, acc[mt][1][3] + bc1.w);
                    *(float4*)(o + 16 + q * 4) = v1;
                }
            }
        }
    }
}

extern "C" void kernel_launch(void* const* d_in, const int* in_sizes, int n_in,
                              void* d_out, int out_size, void* d_ws, size_t ws_size,
                              hipStream_t stream) {
    const float* x  = (const float*)d_in[0];
    const float* w1 = (const float*)d_in[1];
    const float* b1 = (const float*)d_in[2];
    const float* wf = (const float*)d_in[3];
    const float* bf = (const float*)d_in[4];
    float* out = (float*)d_out;
    unsigned short* w2pk = (unsigned short*)d_ws;
    float* bcg = (float*)((char*)d_ws + WS_BC_OFF);
    float* Eg  = (float*)((char*)d_ws + WS_E_OFF);
    float* w1t = (float*)((char*)d_ws + WS_W1T_OFF);

    hipLaunchKernelGGL(pre_kernel, dim3(120), dim3(256), 0, stream, w1, w1t, w2pk);
    hipLaunchKernelGGL(prep_kernel, dim3(606), dim3(256), 0, stream,
                       w1t, b1, wf, bf, w2pk, bcg, Eg);
    hipLaunchKernelGGL(main_kernel, dim3(17, B_), dim3(256), 0, stream,
                       x, w2pk, bcg, out, Eg);
}